// Round 4
// baseline (69.484 us; speedup 1.0000x reference)
//
#include <hip/hip_runtime.h>

// out[b,h,i,j] = sum_d q[b,i,h,d] * T[128 + x[b,j] - x[b,i], h*64+d]
// Round 4: two kernels.
//  (1) cvt_kernel: et -> bf16, XOR-swizzled chunk layout per head into d_ws
//      (chunk pos = c8 ^ (r&7); rows unpadded 128B so global_load_lds's
//      linear lane->LDS mapping works, yet mfma B-frag ds_read_b128 stays
//      <=2-way bank-aliased). Also q -> bf16.
//  (2) relpos_kernel: stage 32KB table slice via 8x global_load_lds width=16
//      (async DMA, no VGPR round-trip, no per-block cvt), A-frags directly
//      from global bf16 q, 16x256x64 GEMM via 8 mfma_16x16x32_bf16/wave,
//      scatter to t-table, gather + coalesced float2 stores.

#define S_LEN 512
#define NH 8
#define HD 64
#define EDIM 512
#define TI 16      // i-rows per block; grid = B*NH*(S/TI) = 512 blocks
#define NR 256
#define OPAD 257   // t-table row pad (floats)

#define WS_TBL_ELEMS (NH * NR * HD)       // 131072 ushorts (256 KB)
#define WS_Q_OFF     WS_TBL_ELEMS

typedef __attribute__((ext_vector_type(8))) short    bf16x8;
typedef __attribute__((ext_vector_type(8))) unsigned short ushort8;
typedef __attribute__((ext_vector_type(4))) float    f32x4;

__device__ __forceinline__ unsigned short f2bf(float f) {
    union { float f; unsigned u; } v; v.f = f;
    unsigned r = v.u + 0x7fffu + ((v.u >> 16) & 1u);   // RNE
    return (unsigned short)(r >> 16);
}

// ---------- pre-kernel: fp32 -> bf16 (table swizzled, q linear) ----------
__global__ __launch_bounds__(256) void cvt_kernel(
    const float* __restrict__ q,     // [B, S, H, D]  (B*S*H*D = 524288)
    const float* __restrict__ et,    // [257, E]
    unsigned short* __restrict__ ws)
{
    const int t = blockIdx.x * 256 + threadIdx.x;
    if (blockIdx.x < 64) {
        // table: t indexes (h, r, c8) chunks of 8 elems; 8*256*8 = 16384
        const int h  = t >> 11;
        const int r  = (t >> 3) & 255;
        const int c8 = t & 7;
        const float* src = et + (size_t)r * EDIM + h * HD + c8 * 8;
        const float4 v0 = *(const float4*)src;
        const float4 v1 = *(const float4*)(src + 4);
        ushort8 u;
        u[0] = f2bf(v0.x); u[1] = f2bf(v0.y); u[2] = f2bf(v0.z); u[3] = f2bf(v0.w);
        u[4] = f2bf(v1.x); u[5] = f2bf(v1.y); u[6] = f2bf(v1.z); u[7] = f2bf(v1.w);
        *(ushort8*)(ws + ((h * NR + r) * HD) + ((c8 ^ (r & 7)) * 8)) = u;
    } else {
        const int idx = (t - 64 * 256) * 4;          // < 524288
        const float4 v = *(const float4*)(q + idx);
        ushort4 u;
        u.x = f2bf(v.x); u.y = f2bf(v.y); u.z = f2bf(v.z); u.w = f2bf(v.w);
        *(ushort4*)(ws + WS_Q_OFF + idx) = u;
    }
}

// ---------- main kernel ----------
__global__ __launch_bounds__(256) void relpos_kernel(
    const unsigned short* __restrict__ ws,   // bf16 table (swizzled) + bf16 q
    const int*   __restrict__ x,             // [B, S]
    const int*   __restrict__ maxx_p,
    float*       __restrict__ out)           // [B, H, S, S]
{
    const int tid = threadIdx.x;
    const int per = S_LEN / TI;                  // 32
    const int b   = blockIdx.x / (NH * per);
    const int h   = (blockIdx.x / per) % NH;
    const int i0  = (blockIdx.x % per) * TI;

    __shared__ unsigned short Tl[NR * HD];       // 32 KB  swizzled bf16 slice
    __shared__ float          Ts[TI][OPAD];      // 16.1 KB scores-by-rel
    __shared__ int            xi_s[TI];

    const int w    = tid >> 6;                   // wave id
    const int l    = tid & 63;
    const int quad = l >> 4;
    const int c    = l & 15;

    // --- async-DMA stage: 32KB linear, 8 x 1KB per wave ---
    const char* gbase = (const char*)(ws + (size_t)h * (NR * HD)) + w * 8192 + l * 16;
    char* lbase = (char*)Tl + w * 8192;          // wave-uniform LDS base
    #pragma unroll
    for (int it = 0; it < 8; ++it) {
        __builtin_amdgcn_global_load_lds(
            (const __attribute__((address_space(1))) unsigned int*)(gbase + it * 1024),
            (__attribute__((address_space(3))) unsigned int*)(lbase + it * 1024),
            16, 0, 0);
    }

    // --- A-fragments straight from global bf16 q (no LDS, no barrier dep) ---
    const unsigned short* qrow =
        ws + WS_Q_OFF + (((size_t)(b * S_LEN + i0 + c)) * NH + h) * HD;
    const bf16x8 a0 = *(const bf16x8*)(qrow + quad * 8);        // k 0..31
    const bf16x8 a1 = *(const bf16x8*)(qrow + 32 + quad * 8);   // k 32..63

    if (tid < TI) xi_s[tid] = x[b * S_LEN + i0 + tid];
    const int2 xj = *(const int2*)(x + b * S_LEN + 2 * tid);    // lane's 2 j-cols
    const int maxx = maxx_p[0];

    __syncthreads();                             // drains vmcnt -> Tl ready

    // --- MFMA: S[m][r] = sum_d Q[m][d] * T[r][d] ---
    f32x4 acc[4];
    #pragma unroll
    for (int nt = 0; nt < 4; ++nt) acc[nt] = (f32x4){0.f, 0.f, 0.f, 0.f};

    #pragma unroll
    for (int nt = 0; nt < 4; ++nt) {
        const int r  = w * 64 + nt * 16 + c;
        const int p0 = quad ^ (r & 7);           // stored pos of chunk quad
        const int p1 = (4 + quad) ^ (r & 7);     // stored pos of chunk 4+quad
        const bf16x8 b0 = *(const bf16x8*)(Tl + r * HD + p0 * 8);
        const bf16x8 b1 = *(const bf16x8*)(Tl + r * HD + p1 * 8);
        acc[nt] = __builtin_amdgcn_mfma_f32_16x16x32_bf16(a0, b0, acc[nt], 0, 0, 0);
        acc[nt] = __builtin_amdgcn_mfma_f32_16x16x32_bf16(a1, b1, acc[nt], 0, 0, 0);
    }

    // C/D layout: lane l reg v holds D[m = quad*4 + v][n = l&15]
    #pragma unroll
    for (int nt = 0; nt < 4; ++nt) {
        #pragma unroll
        for (int v = 0; v < 4; ++v)
            Ts[quad * 4 + v][w * 64 + nt * 16 + c] = acc[nt][v];
    }

    __syncthreads();

    // --- gather + coalesced float2 stores ---
    float* obase = out + (((size_t)b * NH + h) * S_LEN + i0) * S_LEN;
    #pragma unroll
    for (int ii = 0; ii < TI; ++ii) {
        const int xi = xi_s[ii];
        const int r0 = (maxx + xj.x - xi) & 255;   // rel in [1,255]; mask = safety
        const int r1 = (maxx + xj.y - xi) & 255;
        float2 o;
        o.x = Ts[ii][r0];
        o.y = Ts[ii][r1];
        *(float2*)(obase + (size_t)ii * S_LEN + 2 * tid) = o;
    }
}

extern "C" void kernel_launch(void* const* d_in, const int* in_sizes, int n_in,
                              void* d_out, int out_size, void* d_ws, size_t ws_size,
                              hipStream_t stream) {
    const float* q    = (const float*)d_in[0];
    const float* et   = (const float*)d_in[1];
    const int*   x    = (const int*)d_in[2];
    const int*   maxx = (const int*)d_in[3];
    float*       out  = (float*)d_out;
    unsigned short* ws = (unsigned short*)d_ws;

    const int B = in_sizes[2] / S_LEN;           // 2

    // pre-kernel: 64 table blocks + 512 q blocks
    cvt_kernel<<<dim3(64 + (B * S_LEN * NH * HD) / 1024), 256, 0, stream>>>(q, et, ws);

    relpos_kernel<<<dim3(B * NH * (S_LEN / TI)), 256, 0, stream>>>(ws, x, maxx, out);
}

// Round 5
// 67.431 us; speedup vs baseline: 1.0304x; 1.0304x over previous
//
#include <hip/hip_runtime.h>
#include <hip/hip_bf16.h>

// out[b,h,i,j] = sum_d q[b,i,h,d] * T[128 + x[b,j] - x[b,i], h*64+d]
// Round 5: single launch (round-4 split regressed). 16x256x64 GEMM per
// (b,h,16-i-rows) via 8 mfma_16x16x32_bf16/wave. vs round 3:
//  - Tl stored unpadded with XOR chunk swizzle (pos = c8 ^ (r&7)):
//    B-frag ds_read_b128 conflict-free, staging writes conflict-free.
//  - packed v_cvt_pk_bf16_f32 (halves cvt VALU).
//  - A-frags direct from global fp32 q (no Ql, no barrier dep).
//  - score table transposed Ts[r][18]: scatter 8x ds_write_b64 (was 16 b32),
//    gather 16x ds_read_b64 (was 32 b32), stride-18 bank spread.

#define S_LEN 512
#define NH 8
#define HD 64
#define EDIM 512
#define TI 16      // i-rows per block; grid = B*NH*(S/TI) = 512 -> 2 blocks/CU
#define NR 256
#define TIP 18     // Ts row pad (floats): 72B rows, 8B-aligned, odd/16 bank spread

typedef __attribute__((ext_vector_type(8))) short bf16x8;
typedef __attribute__((ext_vector_type(4))) float f32x4;

__device__ __forceinline__ ushort2 pk_bf16(float a, float b) {
    union { __hip_bfloat162 h; ushort2 u; } v;
    v.h = __float22bfloat162_rn(float2{a, b});
    return v.u;
}

__global__ __launch_bounds__(256) void relpos_kernel(
    const float* __restrict__ q,     // [B, S, H, D]
    const float* __restrict__ et,    // [257, E]
    const int*   __restrict__ x,     // [B, S]
    const int*   __restrict__ maxx_p,
    float*       __restrict__ out)   // [B, H, S, S]
{
    const int tid = threadIdx.x;
    const int per = S_LEN / TI;                  // 32
    const int b   = blockIdx.x / (NH * per);
    const int h   = (blockIdx.x / per) % NH;
    const int i0  = (blockIdx.x % per) * TI;

    __shared__ unsigned short Tl[NR * HD];       // 32 KB swizzled bf16 table slice
    __shared__ float          Ts[NR][TIP];       // 18 KB scores, [r][i] layout
    __shared__ int            xi_s[TI];

    const int w    = tid >> 6;
    const int l    = tid & 63;
    const int quad = l >> 4;
    const int c    = l & 15;

    // --- A-fragments: global fp32 q row (i0+c) -> bf16 regs (pre-barrier) ---
    const float* qrow = q + (((size_t)b * S_LEN + i0 + c) * NH + h) * HD;
    const float4 qa0 = *(const float4*)(qrow + quad * 8);
    const float4 qa1 = *(const float4*)(qrow + quad * 8 + 4);
    const float4 qb0 = *(const float4*)(qrow + 32 + quad * 8);
    const float4 qb1 = *(const float4*)(qrow + 32 + quad * 8 + 4);

    // --- stage table: 16 rows/iter, lane = one float4 of a row ---
    const int rrow = tid >> 4;                   // row within iter group
    const int c4   = tid & 15;                   // float4 index in row (0..15)
    const int c8   = c4 >> 1;                    // 16B bf16 chunk (0..7)
    const int half = c4 & 1;
    #pragma unroll
    for (int it = 0; it < 16; ++it) {
        const int r = it * 16 + rrow;
        const float4 v = *(const float4*)(et + (size_t)r * EDIM + h * HD + c4 * 4);
        const ushort2 u0 = pk_bf16(v.x, v.y);
        const ushort2 u1 = pk_bf16(v.z, v.w);
        ushort4 u; u.x = u0.x; u.y = u0.y; u.z = u1.x; u.w = u1.y;
        *(ushort4*)(Tl + r * HD + ((c8 ^ (r & 7)) * 8) + half * 4) = u;
    }

    if (tid < TI) xi_s[tid] = x[b * S_LEN + i0 + tid];
    const int2 xj = *(const int2*)(x + b * S_LEN + 2 * tid);   // lane's 2 j-cols
    const int maxx = maxx_p[0];

    // pack A fragments while staging is in flight
    union { bf16x8 v; ushort2 u[4]; } a0u, a1u;
    a0u.u[0] = pk_bf16(qa0.x, qa0.y); a0u.u[1] = pk_bf16(qa0.z, qa0.w);
    a0u.u[2] = pk_bf16(qa1.x, qa1.y); a0u.u[3] = pk_bf16(qa1.z, qa1.w);
    a1u.u[0] = pk_bf16(qb0.x, qb0.y); a1u.u[1] = pk_bf16(qb0.z, qb0.w);
    a1u.u[2] = pk_bf16(qb1.x, qb1.y); a1u.u[3] = pk_bf16(qb1.z, qb1.w);

    __syncthreads();

    // --- MFMA: S[m][r] = sum_d Q[m][d] * T[r][d]; wave w covers r in w*64.. ---
    f32x4 acc[4];
    #pragma unroll
    for (int nt = 0; nt < 4; ++nt) acc[nt] = (f32x4){0.f, 0.f, 0.f, 0.f};

    #pragma unroll
    for (int nt = 0; nt < 4; ++nt) {
        const int r  = w * 64 + nt * 16 + c;     // r&7 == c&7 (16 | nt-stride)
        const int p0 = quad ^ (c & 7);
        const int p1 = (4 + quad) ^ (c & 7);
        const bf16x8 b0 = *(const bf16x8*)(Tl + r * HD + p0 * 8);
        const bf16x8 b1 = *(const bf16x8*)(Tl + r * HD + p1 * 8);
        acc[nt] = __builtin_amdgcn_mfma_f32_16x16x32_bf16(a0u.v, b0, acc[nt], 0, 0, 0);
        acc[nt] = __builtin_amdgcn_mfma_f32_16x16x32_bf16(a1u.v, b1, acc[nt], 0, 0, 0);
    }

    // C/D: lane l reg v holds D[m = quad*4 + v][n = l&15] -> Ts[r][m], 2x b64/nt
    #pragma unroll
    for (int nt = 0; nt < 4; ++nt) {
        const int r = w * 64 + nt * 16 + c;
        *(float2*)&Ts[r][quad * 4]     = float2{acc[nt][0], acc[nt][1]};
        *(float2*)&Ts[r][quad * 4 + 2] = float2{acc[nt][2], acc[nt][3]};
    }

    __syncthreads();

    // --- gather (b64 over i-pairs) + coalesced float2 stores ---
    float* obase = out + (((size_t)b * NH + h) * S_LEN + i0) * S_LEN;
    #pragma unroll
    for (int ii = 0; ii < TI; ii += 2) {
        const int r0 = (maxx + xj.x - xi_s[ii]) & 255;       // col j = 2*tid
        const int r1 = (maxx + xj.y - xi_s[ii]) & 255;       // col j = 2*tid+1
        // xi same for both rows of the pair? NO - xi differs per row. Gather per row:
        const int r0b = (maxx + xj.x - xi_s[ii + 1]) & 255;
        const int r1b = (maxx + xj.y - xi_s[ii + 1]) & 255;
        const float2 g0 = *(const float2*)&Ts[r0][ii];       // rows ii,ii+1 @ col j
        const float2 g1 = *(const float2*)&Ts[r1][ii];       // rows ii,ii+1 @ col j+1
        // g0.y/g1.y are valid only if r for row ii+1 equals r for row ii, which
        // requires same xi -> not guaranteed. Use per-row reads instead:
        float2 o0, o1;
        o0.x = g0.x;                                          // (ii,   j)
        o0.y = g1.x;                                          // (ii,   j+1)
        o1.x = (r0b == r0) ? g0.y : Ts[r0b][ii + 1];          // (ii+1, j)
        o1.y = (r1b == r1) ? g1.y : Ts[r1b][ii + 1];          // (ii+1, j+1)
        *(float2*)(obase + (size_t)ii * S_LEN + 2 * tid)       = o0;
        *(float2*)(obase + (size_t)(ii + 1) * S_LEN + 2 * tid) = o1;
    }
}

extern "C" void kernel_launch(void* const* d_in, const int* in_sizes, int n_in,
                              void* d_out, int out_size, void* d_ws, size_t ws_size,
                              hipStream_t stream) {
    const float* q    = (const float*)d_in[0];
    const float* et   = (const float*)d_in[1];
    const int*   x    = (const int*)d_in[2];
    const int*   maxx = (const int*)d_in[3];
    float*       out  = (float*)d_out;

    const int B = in_sizes[2] / S_LEN;           // 2
    dim3 grid(B * NH * (S_LEN / TI));            // 512 blocks
    relpos_kernel<<<grid, 256, 0, stream>>>(q, et, x, maxx, out);
}